// Round 1
// baseline (2569.999 us; speedup 1.0000x reference)
//
#include <hip/hip_runtime.h>
#include <hip/hip_bf16.h>

#define NN 100000
#define NE 3200000
#define FIN 512
#define HID 256
#define NC 32
#define KH 10

// ---- edge accessors: mode==1 means data is int64 (little-endian lo/hi pairs) ----
__device__ __forceinline__ int esrc(const int* e, int mode, int i){ return mode ? e[2*i] : e[i]; }
__device__ __forceinline__ int edst(const int* e, int mode, int i){ return mode ? e[2*(NE+i)] : e[NE+i]; }

// Detect int64 vs int32 storage: if int64, every odd 32-bit word (hi word) is 0.
__global__ void k_detect(const int* __restrict__ e, int* __restrict__ flag){
  __shared__ int red[256];
  int t=threadIdx.x; int acc=0;
  for(int i=t;i<4096;i+=256) acc |= e[2*i+1];
  red[t]=acc; __syncthreads();
  for(int s=128;s>0;s>>=1){ if(t<s) red[t]|=red[t+s]; __syncthreads(); }
  if(t==0) flag[0]=(red[0]==0)?1:0;
}

__global__ void k_count(const int* __restrict__ e, const int* __restrict__ flag, int* __restrict__ cnt){
  int i=blockIdx.x*256+threadIdx.x;
  int mode=flag[0];
  if(i<NE) atomicAdd(&cnt[edst(e,mode,i)],1);
}

__global__ void k_dinv(const int* __restrict__ cnt, float* __restrict__ dinv){
  int v=blockIdx.x*256+threadIdx.x;
  if(v<NN) dinv[v]=rsqrtf((float)(cnt[v]+1));
}

// ---- 3-kernel exclusive scan over cnt[] -> rp[] ----
__global__ void k_scan1(const int* __restrict__ cnt, int* __restrict__ rp, int* __restrict__ bsum){
  __shared__ int sums[256];
  int b=blockIdx.x,t=threadIdx.x;
  int base=b*2048+t*8;
  int v[8]; int s=0;
  #pragma unroll
  for(int j=0;j<8;j++){ int idx=base+j; v[j]=(idx<NN)?cnt[idx]:0; s+=v[j]; }
  sums[t]=s; __syncthreads();
  for(int d=1;d<256;d<<=1){ int x=(t>=d)?sums[t-d]:0; __syncthreads(); sums[t]+=x; __syncthreads(); }
  int run=sums[t]-s;
  #pragma unroll
  for(int j=0;j<8;j++){ int idx=base+j; if(idx<NN) rp[idx]=run; run+=v[j]; }
  if(t==255) bsum[b]=sums[255];
}

__global__ void k_scan2(int* __restrict__ bsum, int nb){
  int run=0;
  for(int i=0;i<nb;i++){ int x=bsum[i]; bsum[i]=run; run+=x; }
}

__global__ void k_scan3(int* __restrict__ rp, const int* __restrict__ bsum, int* __restrict__ rfill){
  int i=blockIdx.x*256+threadIdx.x;
  if(i<NN){ int v=rp[i]+bsum[i>>11]; rp[i]=v; rfill[i]=v; }
  if(i==0) rp[NN]=NE;
}

__global__ void k_fill(const int* __restrict__ e, const int* __restrict__ flag,
                       const float* __restrict__ dinv, int* __restrict__ rfill, int2* __restrict__ ep){
  int i=blockIdx.x*256+threadIdx.x;
  int mode=flag[0];
  if(i<NE){
    int s=esrc(e,mode,i), d=edst(e,mode,i);
    int pos=atomicAdd(&rfill[d],1);
    ep[pos]=make_int2(s,__float_as_int(dinv[s]*dinv[d]));
  }
}

// ---- GEMM1: h1 = relu(x @ W1 + b1), stored bf16. 64x64 tile, 4x4/thread, f32 FMA ----
__global__ __launch_bounds__(256) void k_gemm1(const float* __restrict__ x, const float* __restrict__ W1,
                                               const float* __restrict__ b1, __hip_bfloat16* __restrict__ h1){
  __shared__ float As[64][33];
  __shared__ float Bs[32][64];
  int t=threadIdx.x, ty=t>>4, tx=t&15;
  int rb=blockIdx.x*64, cb=blockIdx.y*64;
  float acc[4][4]={};
  for(int k0=0;k0<FIN;k0+=32){
    #pragma unroll
    for(int l=0;l<2;l++){
      int slot=t+l*256;
      int r=slot>>3, c=(slot&7)*4;
      int gr=rb+r;
      float4 a = (gr<NN)? *(const float4*)(x+(size_t)gr*FIN+k0+c) : make_float4(0.f,0.f,0.f,0.f);
      As[r][c]=a.x; As[r][c+1]=a.y; As[r][c+2]=a.z; As[r][c+3]=a.w;
    }
    #pragma unroll
    for(int l=0;l<2;l++){
      int slot=t+l*256;
      int r=slot>>4, c=(slot&15)*4;
      *(float4*)&Bs[r][c] = *(const float4*)(W1+(size_t)(k0+r)*HID+cb+c);
    }
    __syncthreads();
    #pragma unroll
    for(int k=0;k<32;k++){
      float a[4],bb[4];
      #pragma unroll
      for(int i=0;i<4;i++) a[i]=As[ty*4+i][k];
      #pragma unroll
      for(int j=0;j<4;j++) bb[j]=Bs[k][tx*4+j];
      #pragma unroll
      for(int i=0;i<4;i++)
        #pragma unroll
        for(int j=0;j<4;j++) acc[i][j]+=a[i]*bb[j];
    }
    __syncthreads();
  }
  #pragma unroll
  for(int i=0;i<4;i++){
    int gr=rb+ty*4+i;
    if(gr<NN){
      #pragma unroll
      for(int j=0;j<4;j++){
        int gc=cb+tx*4+j;
        float v=acc[i][j]+b1[gc];
        v = v>0.f ? v : 0.f;
        h1[(size_t)gr*HID+gc]=__float2bfloat16(v);
      }
    }
  }
}

// ---- GEMM2: h = h1 @ W2 + b2 ; acc = gamma[0]*h (fused init) ----
__global__ __launch_bounds__(256) void k_gemm2(const __hip_bfloat16* __restrict__ h1, const float* __restrict__ W2,
                                               const float* __restrict__ b2, const float* __restrict__ gamma,
                                               float* __restrict__ h, float* __restrict__ acc){
  __shared__ float Ws[HID*NC];
  int t=threadIdx.x;
  for(int i=t;i<HID*NC;i+=256) Ws[i]=W2[i];
  __syncthreads();
  int col=t&31, rg=t>>5;
  int rbase=blockIdx.x*64;
  float g0=gamma[0];
  float bb=b2[col];
  for(int rr=0;rr<8;rr++){
    int r=rbase+rg*8+rr;
    if(r<NN){
      const __hip_bfloat16* hp=h1+(size_t)r*HID;
      float a=bb;
      for(int k=0;k<HID;k++) a += __bfloat162float(hp[k])*Ws[k*NC+col];
      h[r*NC+col]=a;
      acc[r*NC+col]=g0*a;
    }
  }
}

// ---- propagation: pull over CSR, 32 lanes = 32 classes per node ----
__global__ __launch_bounds__(256) void k_prop(const float* __restrict__ hcur, float* __restrict__ hnext,
                                              float* __restrict__ acc, const float* __restrict__ gamma, int step,
                                              const int* __restrict__ rp, const int2* __restrict__ ep,
                                              const float* __restrict__ dinv){
  int t=threadIdx.x, c=t&31, g=t>>5;
  int v=blockIdx.x*8+g;
  float dv=dinv[v];
  float a=dv*dv*hcur[v*NC+c];
  int e0=rp[v], e1=rp[v+1];
  for(int e=e0;e<e1;e++){
    int2 sw=ep[e];
    a += __int_as_float(sw.y)*hcur[sw.x*NC+c];
  }
  hnext[v*NC+c]=a;
  acc[v*NC+c]+=gamma[step]*a;
}

__global__ __launch_bounds__(256) void k_lsm(const float* __restrict__ acc, float* __restrict__ out){
  int t=threadIdx.x, c=t&31, g=t>>5;
  int v=blockIdx.x*8+g;
  float xv=acc[v*NC+c];
  float m=xv;
  #pragma unroll
  for(int o=16;o>0;o>>=1) m=fmaxf(m,__shfl_xor(m,o,32));
  float ex=expf(xv-m);
  float s=ex;
  #pragma unroll
  for(int o=16;o>0;o>>=1) s+=__shfl_xor(s,o,32);
  out[v*NC+c]=xv-m-logf(s);
}

extern "C" void kernel_launch(void* const* d_in, const int* in_sizes, int n_in,
                              void* d_out, int out_size, void* d_ws, size_t ws_size,
                              hipStream_t stream){
  const float* x    =(const float*)d_in[0];
  const int*   e    =(const int*)  d_in[1];
  const float* W1   =(const float*)d_in[2];
  const float* b1   =(const float*)d_in[3];
  const float* W2   =(const float*)d_in[4];
  const float* b2   =(const float*)d_in[5];
  const float* gamma=(const float*)d_in[6];
  float* out=(float*)d_out;
  char* ws=(char*)d_ws;

  size_t off=0;
  auto alloc=[&](size_t b){ size_t o=off; off+=(b+255)&~(size_t)255; return o; };
  __hip_bfloat16* h1 =(__hip_bfloat16*)(ws+alloc((size_t)NN*HID*2));
  float* hb0 =(float*)(ws+alloc((size_t)NN*NC*4));
  float* hb1 =(float*)(ws+alloc((size_t)NN*NC*4));
  float* accb=(float*)(ws+alloc((size_t)NN*NC*4));
  float* dinv=(float*)(ws+alloc((size_t)NN*4));
  int*   cnt =(int*)  (ws+alloc((size_t)NN*4));
  int*   rp  =(int*)  (ws+alloc((size_t)(NN+1)*4));
  int*   rfill=(int*) (ws+alloc((size_t)NN*4));
  int*   bsum=(int*)  (ws+alloc(4096));
  int*   flag=(int*)  (ws+alloc(256));
  int2*  ep  =(int2*) (ws+alloc((size_t)NE*8));

  hipMemsetAsync(cnt,0,(size_t)NN*4,stream);
  k_detect<<<1,256,0,stream>>>(e,flag);
  k_count<<<(NE+255)/256,256,0,stream>>>(e,flag,cnt);
  k_dinv<<<(NN+255)/256,256,0,stream>>>(cnt,dinv);
  int nb=(NN+2047)/2048;
  k_scan1<<<nb,256,0,stream>>>(cnt,rp,bsum);
  k_scan2<<<1,1,0,stream>>>(bsum,nb);
  k_scan3<<<(NN+255)/256,256,0,stream>>>(rp,bsum,rfill);
  k_fill<<<(NE+255)/256,256,0,stream>>>(e,flag,dinv,rfill,ep);

  k_gemm1<<<dim3((NN+63)/64,HID/64),256,0,stream>>>(x,W1,b1,h1);
  k_gemm2<<<(NN+63)/64,256,0,stream>>>(h1,W2,b2,gamma,hb0,accb);

  float* cur=hb0; float* nxt=hb1;
  for(int k=1;k<=KH;k++){
    k_prop<<<NN/8,256,0,stream>>>(cur,nxt,accb,gamma,k,rp,ep,dinv);
    float* tmp=cur; cur=nxt; nxt=tmp;
  }
  k_lsm<<<NN/8,256,0,stream>>>(accb,out);
}